// Round 7
// baseline (503.130 us; speedup 1.0000x reference)
//
#include <hip/hip_runtime.h>

typedef __attribute__((ext_vector_type(4))) float  f4;
typedef __attribute__((ext_vector_type(8))) short  bf16x8;
typedef __attribute__((ext_vector_type(4))) float  f32x4;
typedef __attribute__((ext_vector_type(4))) unsigned short us4;
typedef __attribute__((ext_vector_type(2))) unsigned int u32x2;
typedef __attribute__((ext_vector_type(4))) unsigned int u32x4;

#define BATCH 64
#define FEAT 2048
#define NC_C 112
#define TE 1024          // 2*E
#define EE 512
#define NCLS 345
#define NCLSP 352
#define KHEAD 57344      // C*E

__device__ __forceinline__ unsigned short f2bf(float f) {
    unsigned u = __float_as_uint(f);
    unsigned r = (u + 0x7FFFu + ((u >> 16) & 1u)) >> 16;
    return (unsigned short)r;
}
__device__ __forceinline__ float bf2f(unsigned short h) {
    return __uint_as_float(((unsigned)h) << 16);
}
__device__ __forceinline__ unsigned cvtpk(float a, float b) {
    unsigned r;
    asm("v_cvt_pk_bf16_f32 %0, %1, %2" : "=v"(r) : "v"(a), "v"(b));
    return r;
}

// ---------------------------------------------------------------------------
// K1: split-K partial GEMM with CONTIGUOUS W streaming.
// block = (c = bid>>3, ks = bid&7); K-slice 256; FULL n = 1024.
// Per k32 step the block stages W rows [32s,32s+32) x 1024 cols = 128KB of
// perfectly sequential HBM (each wave-instr = 64 lanes x 16B = 1KB contig).
// B goes into the R1/R6-PROVEN [n][k] stride-40 XOR-octet LDS layout; the
// fragment read formula is byte-identical to the verified kernels.
// A-fragments are read per-step from x (f32, L2-hot) - full K=32, no padding.
// 8 waves; wave w owns all 64 m-rows x cols [128w,128w+128).
// Output: bf16 partials pbe[ks][m][c][e] (identical to R6).
// ---------------------------------------------------------------------------
__global__ __launch_bounds__(512) void k_emb(
    const float* __restrict__ x, const float* __restrict__ W_emb,
    unsigned short* __restrict__ pbe)
{
    __shared__ __align__(16) unsigned short Blds[1024 * 40];   // 80 KiB

    const int tid = threadIdx.x;
    const int c  = blockIdx.x >> 3;
    const int ks = blockIdx.x & 7;
    const float* __restrict__ Wc =
        W_emb + (size_t)c * (FEAT * TE) + (size_t)(ks * 256) * TE;

    const int w = tid >> 6, l = tid & 63;
    const int lm = l & 15, kg = l >> 4;       // kg 0..3
    const int wn = w * 128;                   // wave's n-window

    // staging map: thread stages k-rows [4w, 4w+4) (ko == w), cols no*4 + g*256
    const int no = l;                         // 0..63
    const int koct_w = w >> 1;                // octet of rows 4w..4w+3
    const int klo_w  = (w & 1) * 4;

    f32x4 acc[4][8];
#pragma unroll
    for (int mf = 0; mf < 4; ++mf)
#pragma unroll
        for (int nf = 0; nf < 8; ++nf) acc[mf][nf] = (f32x4){0.f, 0.f, 0.f, 0.f};

    // ---- staging: 16 f4 reads (row-major, contiguous) ----
    auto loadB = [&](f4* R, int s) {
        const float* base = Wc + (size_t)(s * 32 + 4 * w) * TE + no * 4;
#pragma unroll
        for (int kk = 0; kk < 4; ++kk)
#pragma unroll
            for (int g = 0; g < 4; ++g)
                R[g * 4 + kk] = *(const f4*)(base + (size_t)kk * TE + g * 256);
    };
    // ---- LDS write into [n][k] stride-40 XOR-octet layout (proven) ----
    auto writeB = [&](const f4* R) {
#pragma unroll
        for (int g = 0; g < 4; ++g)
#pragma unroll
            for (int ni = 0; ni < 4; ++ni) {
                const int n = g * 256 + no * 4 + ni;
                u32x2 v;
                v[0] = cvtpk(R[g * 4 + 0][ni], R[g * 4 + 1][ni]);
                v[1] = cvtpk(R[g * 4 + 2][ni], R[g * 4 + 3][ni]);
                *(u32x2*)&Blds[n * 40 + (((koct_w ^ ((n >> 2) & 3)) << 3) | klo_w)] = v;
            }
    };

    auto compute = [&](int s) {
        const int kofs = ks * 256 + s * 32;
        bf16x8 afr[4];
#pragma unroll
        for (int mf = 0; mf < 4; ++mf) {
            const float* ap = x + (size_t)(mf * 16 + lm) * FEAT + kofs + kg * 8;
            const f4 a0 = *(const f4*)ap;
            const f4 a1 = *(const f4*)(ap + 4);
            u32x4 q;
            q[0] = cvtpk(a0[0], a0[1]); q[1] = cvtpk(a0[2], a0[3]);
            q[2] = cvtpk(a1[0], a1[1]); q[3] = cvtpk(a1[2], a1[3]);
            afr[mf] = __builtin_bit_cast(bf16x8, q);
        }
#pragma unroll
        for (int nf = 0; nf < 8; ++nf) {
            const int n = wn + nf * 16 + lm;
            const bf16x8 bfr =
                *(const bf16x8*)&Blds[n * 40 + (((kg ^ ((n >> 2) & 3)) << 3))];
#pragma unroll
            for (int mf = 0; mf < 4; ++mf)
                acc[mf][nf] = __builtin_amdgcn_mfma_f32_16x16x32_bf16(
                    afr[mf], bfr, acc[mf][nf], 0, 0, 0);
        }
    };

    f4 R[16];
    loadB(R, 0);

    for (int s = 0; s < 8; ++s) {
        __syncthreads();                 // prior compute's LDS reads done
        writeB(R);
        __syncthreads();                 // writes visible
        if (s < 7) loadB(R, s + 1);      // next-step loads fly under compute
        compute(s);
    }

    // store bf16 partials: pbe[ks][m][c][e]  (same formula class as R6)
#pragma unroll
    for (int mf = 0; mf < 4; ++mf)
#pragma unroll
        for (int nf = 0; nf < 8; ++nf) {
            const int e = wn + nf * 16 + lm;
#pragma unroll
            for (int r = 0; r < 4; ++r) {
                const int m = mf * 16 + kg * 4 + r;
                pbe[((size_t)(ks * 64 + m) * NC_C + c) * TE + e] = f2bf(acc[mf][nf][r]);
            }
        }
}

// ---------------------------------------------------------------------------
// K2: reduce 8 partials + bias -> emb; p_int = sigmoid(emb . W_pint + b);
// mixed = p*pos + (1-p)*neg -> flat. one wave per (b,c)   [verified R6]
// ---------------------------------------------------------------------------
__global__ __launch_bounds__(256) void k_mix(
    const unsigned short* __restrict__ pbe, const float* __restrict__ b_emb,
    const float* __restrict__ W_pint, const float* __restrict__ b_pint,
    float* __restrict__ flat_out, float* __restrict__ p_out)
{
    const int tid = threadIdx.x;
    const int l = tid & 63, w = tid >> 6;
    const int pidx = blockIdx.x * 4 + w;
    const int b = pidx / NC_C, c = pidx - b * NC_C;

    float vals[16];
#pragma unroll
    for (int i = 0; i < 4; ++i) {
        const f4 bi = *(const f4*)&b_emb[c * TE + 4 * l + 256 * i];
#pragma unroll
        for (int j = 0; j < 4; ++j) vals[4 * i + j] = bi[j];
    }
#pragma unroll
    for (int ksl = 0; ksl < 8; ++ksl) {
        const unsigned short* __restrict__ rp =
            pbe + ((size_t)(ksl * 64 + b) * NC_C + c) * TE;
#pragma unroll
        for (int i = 0; i < 4; ++i) {
            us4 u = *(const us4*)&rp[4 * l + 256 * i];
#pragma unroll
            for (int j = 0; j < 4; ++j) vals[4 * i + j] += bf2f(u[j]);
        }
    }

    const float* __restrict__ wp = W_pint + c * TE;
    float dot = 0.f;
#pragma unroll
    for (int i = 0; i < 4; ++i) {
        const f4 wv = *(const f4*)&wp[4 * l + 256 * i];
#pragma unroll
        for (int j = 0; j < 4; ++j) dot += vals[4 * i + j] * wv[j];
    }
#pragma unroll
    for (int m = 32; m >= 1; m >>= 1) dot += __shfl_xor(dot, m);
    const float logit = dot + b_pint[c];
    const float p = 1.f / (1.f + __expf(-logit));
    if (l == 0) p_out[b * NC_C + c] = p;

    float* __restrict__ fo = flat_out + (size_t)b * KHEAD + c * EE;
#pragma unroll
    for (int i = 0; i < 2; ++i) {
        f4 m;
#pragma unroll
        for (int j = 0; j < 4; ++j)
            m[j] = p * vals[i * 4 + j] + (1.f - p) * vals[(i + 2) * 4 + j];
        *(f4*)&fo[4 * l + 256 * i] = m;
    }
}

// ---------------------------------------------------------------------------
// K3: partial = flat @ W_head (split-K, atomic-free) -> pbuf[blk][64][352]
// ---------------------------------------------------------------------------
__global__ __launch_bounds__(256) void k_head(
    const float* __restrict__ flat, const float* __restrict__ W_head,
    float* __restrict__ pbuf, int nsteps)
{
    __shared__ __align__(16) unsigned short Blds[NCLSP * 40];

    const int tid = threadIdx.x;
    const int w = tid >> 6, l = tid & 63;
    const int k0 = blockIdx.x * (nsteps * 32);

    f32x4 acc[22];
#pragma unroll
    for (int i = 0; i < 22; ++i) acc[i] = (f32x4){0.f, 0.f, 0.f, 0.f};

    for (int s = 0; s < nsteps; ++s) {
        const int kb = k0 + s * 32;
        __syncthreads();
        for (int idx = tid; idx < 32 * NCLSP; idx += 256) {
            const int k = idx / NCLSP;
            const int n = idx - k * NCLSP;
            const float v = (n < NCLS) ? W_head[(size_t)(kb + k) * NCLS + n] : 0.f;
            Blds[n * 40 + ((((k >> 3) ^ ((n >> 2) & 3)) << 3) | (k & 7))] = f2bf(v);
        }
        __syncthreads();

        const float* __restrict__ ap =
            flat + (size_t)(w * 16 + (l & 15)) * KHEAD + kb + (l >> 4) * 8;
        f4 af0 = *(const f4*)ap;
        f4 af1 = *(const f4*)(ap + 4);
        u32x4 pq;
        pq[0] = cvtpk(af0[0], af0[1]); pq[1] = cvtpk(af0[2], af0[3]);
        pq[2] = cvtpk(af1[0], af1[1]); pq[3] = cvtpk(af1[2], af1[3]);
        bf16x8 a = __builtin_bit_cast(bf16x8, pq);

#pragma unroll
        for (int nf = 0; nf < 22; ++nf) {
            const int n = nf * 16 + (l & 15);
            bf16x8 bfr = *(const bf16x8*)&Blds[n * 40 + (((l >> 4) ^ ((n >> 2) & 3)) << 3)];
            acc[nf] = __builtin_amdgcn_mfma_f32_16x16x32_bf16(a, bfr, acc[nf], 0, 0, 0);
        }
    }

    float* __restrict__ pb = pbuf + (size_t)blockIdx.x * (64 * NCLSP);
#pragma unroll
    for (int nf = 0; nf < 22; ++nf) {
        const int n = nf * 16 + (l & 15);
#pragma unroll
        for (int r = 0; r < 4; ++r) {
            const int row = w * 16 + (l >> 4) * 4 + r;
            pb[row * NCLSP + n] = acc[nf][r];
        }
    }
}

// ---------------------------------------------------------------------------
// K4: final = b_head + sum_p partial[p]
// ---------------------------------------------------------------------------
__global__ __launch_bounds__(256) void k_reduce(
    const float* __restrict__ pbuf, const float* __restrict__ b_head,
    float* __restrict__ final_out, int nb)
{
    const int i = blockIdx.x * 256 + threadIdx.x;
    if (i >= BATCH * NCLS) return;
    const int m = i / NCLS, n = i - m * NCLS;
    float s = b_head[n];
    for (int p = 0; p < nb; ++p)
        s += pbuf[((size_t)p * 64 + m) * NCLSP + n];
    final_out[i] = s;
}

extern "C" void kernel_launch(void* const* d_in, const int* in_sizes, int n_in,
                              void* d_out, int out_size, void* d_ws, size_t ws_size,
                              hipStream_t stream) {
    const float* x      = (const float*)d_in[0];
    const float* W_emb  = (const float*)d_in[1];
    const float* b_emb  = (const float*)d_in[2];
    const float* W_pint = (const float*)d_in[3];
    const float* b_pint = (const float*)d_in[4];
    const float* W_head = (const float*)d_in[5];
    const float* b_head = (const float*)d_in[6];

    float* out       = (float*)d_out;
    float* final_out = out;                                   // 64*345
    float* flat      = out + BATCH * NCLS;                    // 64*57344
    float* p_out     = out + BATCH * NCLS + BATCH * KHEAD;    // 64*112

    // ws layout: [0,117.5MB) emb bf16 partials; [120MiB,+19.3MiB) head partials
    unsigned short* pbe = (unsigned short*)d_ws;
    float* pbuf_h = (float*)((char*)d_ws + (size_t)120 * 1024 * 1024);

    const int NB = 224, nsteps = 8;

    k_emb<<<NC_C * 8, 512, 0, stream>>>(x, W_emb, pbe);
    k_mix<<<(BATCH * NC_C) / 4, 256, 0, stream>>>(pbe, b_emb, W_pint, b_pint, flat, p_out);
    k_head<<<NB, 256, 0, stream>>>(flat, W_head, pbuf_h, nsteps);
    k_reduce<<<(BATCH * NCLS + 255) / 256, 256, 0, stream>>>(pbuf_h, b_head, final_out, NB);
}

// Round 8
// 456.938 us; speedup vs baseline: 1.1011x; 1.1011x over previous
//
#include <hip/hip_runtime.h>

typedef __attribute__((ext_vector_type(4))) float  f4;
typedef __attribute__((ext_vector_type(8))) short  bf16x8;
typedef __attribute__((ext_vector_type(4))) float  f32x4;
typedef __attribute__((ext_vector_type(4))) unsigned short us4;
typedef __attribute__((ext_vector_type(2))) unsigned int u32x2;
typedef __attribute__((ext_vector_type(4))) unsigned int u32x4;

#define BATCH 64
#define FEAT 2048
#define NC_C 112
#define TE 1024          // 2*E
#define EE 512
#define NCLS 345
#define NCLSP 352
#define KHEAD 57344      // C*E

__device__ __forceinline__ unsigned short f2bf(float f) {
    unsigned u = __float_as_uint(f);
    unsigned r = (u + 0x7FFFu + ((u >> 16) & 1u)) >> 16;
    return (unsigned short)r;
}
__device__ __forceinline__ float bf2f(unsigned short h) {
    return __uint_as_float(((unsigned)h) << 16);
}
__device__ __forceinline__ unsigned cvtpk(float a, float b) {
    unsigned r;
    asm("v_cvt_pk_bf16_f32 %0, %1, %2" : "=v"(r) : "v"(a), "v"(b));
    return r;
}
// non-temporal helpers (streaming, no cache allocation)
__device__ __forceinline__ f4 ntl4(const float* p) {
    return __builtin_nontemporal_load((const f4*)p);
}
__device__ __forceinline__ us4 ntlu4(const unsigned short* p) {
    return __builtin_nontemporal_load((const us4*)p);
}

// ---------------------------------------------------------------------------
// K1: embeddings = x @ W_emb[c] + b_emb (per c), bf16 MFMA, 64x128 tiles.
// IDENTICAL to the verified R1 kernel (416us) except: W_emb staging loads and
// the emb_bf epilogue stores are NON-TEMPORAL (zero-reuse streams).
// grid 896 = 112 c * 8 n-tiles, block 256 (4 waves, 2x2 over 64x128).
// ---------------------------------------------------------------------------
__global__ __launch_bounds__(256) void k_emb(
    const float* __restrict__ x, const float* __restrict__ W_emb,
    const float* __restrict__ b_emb, unsigned short* __restrict__ emb_bf)
{
    __shared__ __align__(16) unsigned short Alds[64 * 40];   // [row][k] stride 40
    __shared__ __align__(16) unsigned short Blds[128 * 40];  // [n][k] swizzled

    const int tid = threadIdx.x;
    const int c  = blockIdx.x >> 3;
    const int n0 = (blockIdx.x & 7) * 128;
    const float* __restrict__ Wc = W_emb + (size_t)c * (FEAT * TE);

    const int w = tid >> 6, l = tid & 63;
    const int mbase = (w & 1) * 32, nbase = (w >> 1) * 64;

    const int a_row = tid >> 3;           // 0..31 (+32 second row)
    const int a_k4  = (tid & 7) * 4;
    const int b_kp  = tid >> 4;           // 0..15
    const int b_n4  = (tid & 15) * 4;

    const float* __restrict__ axp = x + (size_t)a_row * FEAT + a_k4;
    const float* __restrict__ bpp = Wc + (size_t)(2 * b_kp) * TE + n0 + b_n4;

    unsigned short* __restrict__ aw0 = &Alds[a_row * 40 + a_k4];
    unsigned short* __restrict__ aw1 = &Alds[(a_row + 32) * 40 + a_k4];
    const int koct = b_kp >> 2, klo = (2 * b_kp) & 7;

    auto ke_load = [&](f4& A0, f4& A1, f4& B0, f4& B1, f4& B2, f4& B3, int kstep) {
        const float* ax_ = axp + kstep * 32;
        A0 = *(const f4*)ax_;                          // x: reused, cached
        A1 = *(const f4*)(ax_ + 32 * FEAT);
        const float* bp_ = bpp + (size_t)kstep * 32 * TE;
        B0 = ntl4(bp_);            B1 = ntl4(bp_ + TE);      // W: stream, nt
        B2 = ntl4(bp_ + 64);       B3 = ntl4(bp_ + TE + 64);
    };
    auto ke_write = [&](const f4& A0, const f4& A1, const f4& B0, const f4& B1,
                        const f4& B2, const f4& B3) {
        u32x2 v0, v1;
        v0[0] = cvtpk(A0[0], A0[1]); v0[1] = cvtpk(A0[2], A0[3]);
        v1[0] = cvtpk(A1[0], A1[1]); v1[1] = cvtpk(A1[2], A1[3]);
        *(u32x2*)aw0 = v0;
        *(u32x2*)aw1 = v1;
#pragma unroll
        for (int i = 0; i < 4; ++i) {
            int n = b_n4 + i;
            *(unsigned*)&Blds[n * 40 + (((koct ^ ((n >> 2) & 3)) << 3) | klo)] =
                cvtpk(B0[i], B1[i]);
            n += 64;
            *(unsigned*)&Blds[n * 40 + (((koct ^ ((n >> 2) & 3)) << 3) | klo)] =
                cvtpk(B2[i], B3[i]);
        }
    };

    f32x4 acc[2][4];
#pragma unroll
    for (int i = 0; i < 2; ++i)
#pragma unroll
        for (int j = 0; j < 4; ++j) acc[i][j] = (f32x4){0.f, 0.f, 0.f, 0.f};

    auto ke_mfma = [&]() {
        bf16x8 af[2], bfr[4];
#pragma unroll
        for (int si = 0; si < 2; ++si)
            af[si] = *(const bf16x8*)&Alds[(mbase + si * 16 + (l & 15)) * 40 + (l >> 4) * 8];
#pragma unroll
        for (int nf = 0; nf < 4; ++nf) {
            int n = nbase + nf * 16 + (l & 15);
            bfr[nf] = *(const bf16x8*)&Blds[n * 40 + (((l >> 4) ^ ((n >> 2) & 3)) << 3)];
        }
#pragma unroll
        for (int si = 0; si < 2; ++si)
#pragma unroll
            for (int nf = 0; nf < 4; ++nf)
                acc[si][nf] = __builtin_amdgcn_mfma_f32_16x16x32_bf16(
                    af[si], bfr[nf], acc[si][nf], 0, 0, 0);
    };

    f4 a0, a1, p0, p1, p2, p3;
    ke_load(a0, a1, p0, p1, p2, p3, 0);

    for (int s = 0; s < 64; ++s) {
        __syncthreads();
        ke_write(a0, a1, p0, p1, p2, p3);
        __syncthreads();
        if (s < 63) ke_load(a0, a1, p0, p1, p2, p3, s + 1);
        ke_mfma();
    }

    // epilogue: + b_emb, nt-store bf16 (emb layout [b][c][e])
#pragma unroll
    for (int si = 0; si < 2; ++si)
#pragma unroll
        for (int nf = 0; nf < 4; ++nf) {
            const int nl = nbase + nf * 16 + (l & 15);
            const int ng = n0 + nl;
            const float bias = b_emb[c * TE + ng];
#pragma unroll
            for (int r = 0; r < 4; ++r) {
                const int bb = mbase + si * 16 + (l >> 4) * 4 + r;
                const float v = acc[si][nf][r] + bias;
                __builtin_nontemporal_store(
                    f2bf(v), &emb_bf[((size_t)bb * NC_C + c) * TE + ng]);
            }
        }
}

// ---------------------------------------------------------------------------
// K2: p_int = sigmoid(emb . W_pint + b_pint); mixed = p*pos + (1-p)*neg
// one wave per (b,c); grid 1792 * 256.  [R1-verbatim + nt on streams]
// ---------------------------------------------------------------------------
__global__ __launch_bounds__(256) void k_mix(
    const unsigned short* __restrict__ emb_bf, const float* __restrict__ W_pint,
    const float* __restrict__ b_pint, float* __restrict__ flat_out,
    float* __restrict__ p_out)
{
    const int tid = threadIdx.x;
    const int l = tid & 63, w = tid >> 6;
    const int pidx = blockIdx.x * 4 + w;           // 0..7167
    const int b = pidx / NC_C, c = pidx - b * NC_C;

    const unsigned short* __restrict__ row = emb_bf + ((size_t)b * NC_C + c) * TE;
    const float* __restrict__ wp = W_pint + c * TE;

    float vals[16];
    float dot = 0.f;
#pragma unroll
    for (int i = 0; i < 4; ++i) {
        const int e = 4 * l + 256 * i;
        us4 u = ntlu4(&row[e]);                       // stream: read once
        f4  wv = *(const f4*)&wp[e];                  // reused across b: cached
#pragma unroll
        for (int j = 0; j < 4; ++j) {
            float f = bf2f(u[j]);
            vals[i * 4 + j] = f;
            dot += f * wv[j];
        }
    }
#pragma unroll
    for (int m = 32; m >= 1; m >>= 1) dot += __shfl_xor(dot, m);
    const float logit = dot + b_pint[c];
    const float p = 1.f / (1.f + __expf(-logit));
    if (l == 0) p_out[b * NC_C + c] = p;

    float* __restrict__ fo = flat_out + (size_t)b * KHEAD + c * EE;
#pragma unroll
    for (int i = 0; i < 2; ++i) {
        const int e = 4 * l + 256 * i;
        f4 m;
#pragma unroll
        for (int j = 0; j < 4; ++j)
            m[j] = p * vals[i * 4 + j] + (1.f - p) * vals[(i + 2) * 4 + j];
        __builtin_nontemporal_store(m, (f4*)&fo[e]);
    }
}

// ---------------------------------------------------------------------------
// K3: partial = flat @ W_head (split-K, atomic-free) -> pbuf[blk][64][352]
// [R6-verbatim + nt on W_head/flat loads and pbuf stores]
// ---------------------------------------------------------------------------
__global__ __launch_bounds__(256) void k_head(
    const float* __restrict__ flat, const float* __restrict__ W_head,
    float* __restrict__ pbuf, int nsteps)
{
    __shared__ __align__(16) unsigned short Blds[NCLSP * 40];

    const int tid = threadIdx.x;
    const int w = tid >> 6, l = tid & 63;
    const int k0 = blockIdx.x * (nsteps * 32);

    f32x4 acc[22];
#pragma unroll
    for (int i = 0; i < 22; ++i) acc[i] = (f32x4){0.f, 0.f, 0.f, 0.f};

    for (int s = 0; s < nsteps; ++s) {
        const int kb = k0 + s * 32;
        __syncthreads();
        for (int idx = tid; idx < 32 * NCLSP; idx += 256) {
            const int k = idx / NCLSP;
            const int n = idx - k * NCLSP;
            const float v = (n < NCLS)
                ? __builtin_nontemporal_load(&W_head[(size_t)(kb + k) * NCLS + n])
                : 0.f;
            Blds[n * 40 + ((((k >> 3) ^ ((n >> 2) & 3)) << 3) | (k & 7))] = f2bf(v);
        }
        __syncthreads();

        const float* __restrict__ ap =
            flat + (size_t)(w * 16 + (l & 15)) * KHEAD + kb + (l >> 4) * 8;
        f4 af0 = ntl4(ap);
        f4 af1 = ntl4(ap + 4);
        u32x4 pq;
        pq[0] = cvtpk(af0[0], af0[1]); pq[1] = cvtpk(af0[2], af0[3]);
        pq[2] = cvtpk(af1[0], af1[1]); pq[3] = cvtpk(af1[2], af1[3]);
        bf16x8 a = __builtin_bit_cast(bf16x8, pq);

#pragma unroll
        for (int nf = 0; nf < 22; ++nf) {
            const int n = nf * 16 + (l & 15);
            bf16x8 bfr = *(const bf16x8*)&Blds[n * 40 + (((l >> 4) ^ ((n >> 2) & 3)) << 3)];
            acc[nf] = __builtin_amdgcn_mfma_f32_16x16x32_bf16(a, bfr, acc[nf], 0, 0, 0);
        }
    }

    float* __restrict__ pb = pbuf + (size_t)blockIdx.x * (64 * NCLSP);
#pragma unroll
    for (int nf = 0; nf < 22; ++nf) {
        const int n = nf * 16 + (l & 15);
#pragma unroll
        for (int r = 0; r < 4; ++r) {
            const int row = w * 16 + (l >> 4) * 4 + r;
            __builtin_nontemporal_store(acc[nf][r], &pb[row * NCLSP + n]);
        }
    }
}

// ---------------------------------------------------------------------------
// K4: final = b_head + sum_p partial[p]
// ---------------------------------------------------------------------------
__global__ __launch_bounds__(256) void k_reduce(
    const float* __restrict__ pbuf, const float* __restrict__ b_head,
    float* __restrict__ final_out, int nb)
{
    const int i = blockIdx.x * 256 + threadIdx.x;
    if (i >= BATCH * NCLS) return;
    const int m = i / NCLS, n = i - m * NCLS;
    float s = b_head[n];
    for (int p = 0; p < nb; ++p)
        s += __builtin_nontemporal_load(&pbuf[((size_t)p * 64 + m) * NCLSP + n]);
    final_out[i] = s;
}

extern "C" void kernel_launch(void* const* d_in, const int* in_sizes, int n_in,
                              void* d_out, int out_size, void* d_ws, size_t ws_size,
                              hipStream_t stream) {
    const float* x      = (const float*)d_in[0];
    const float* W_emb  = (const float*)d_in[1];
    const float* b_emb  = (const float*)d_in[2];
    const float* W_pint = (const float*)d_in[3];
    const float* b_pint = (const float*)d_in[4];
    const float* W_head = (const float*)d_in[5];
    const float* b_head = (const float*)d_in[6];

    float* out       = (float*)d_out;
    float* final_out = out;                                   // 64*345
    float* flat      = out + BATCH * NCLS;                    // 64*57344
    float* p_out     = out + BATCH * NCLS + BATCH * KHEAD;    // 64*112

    // ws layout: [0,14.7MB) emb_bf; [120MiB,+19.3MiB) head partials
    unsigned short* emb_bf = (unsigned short*)d_ws;
    float* pbuf_h = (float*)((char*)d_ws + (size_t)120 * 1024 * 1024);

    const int NB = 224, nsteps = 8;

    k_emb<<<NC_C * 8, 256, 0, stream>>>(x, W_emb, b_emb, emb_bf);
    k_mix<<<(BATCH * NC_C) / 4, 256, 0, stream>>>(emb_bf, W_pint, b_pint, flat, p_out);
    k_head<<<NB, 256, 0, stream>>>(flat, W_head, pbuf_h, nsteps);
    k_reduce<<<(BATCH * NCLS + 255) / 256, 256, 0, stream>>>(pbuf_h, b_head, final_out, NB);
}